// Round 3
// baseline (121.429 us; speedup 1.0000x reference)
//
#include <hip/hip_runtime.h>
#include <math.h>

#define NBINS 256
#define NB    4096            // fine order-statistic buckets (16x refinement of hist grid)
#define BLK   1024
#define CHUNK (NB / BLK)      // 4
#define NWAVE (BLK / 64)      // 16

__global__ void mask_bits_kernel(const float* __restrict__ masks,
                                 unsigned* __restrict__ bits, int total)
{
    const int idx = blockIdx.x * blockDim.x + threadIdx.x;
    bool m = false;
    if (idx < total) m = (masks[idx] != 0.0f);
    const unsigned long long b = __ballot(m);
    const int lane = threadIdx.x & 63;
    if (idx < total) {
        if (lane == 0)       bits[idx >> 5] = (unsigned)b;
        else if (lane == 32) bits[idx >> 5] = (unsigned)(b >> 32);
    }
}

__global__ __launch_bounds__(BLK, 8) void hist_match_kernel(
    const float* __restrict__ x,      // [C, N]
    const unsigned* __restrict__ bits,// [S, N/32]
    const float* __restrict__ thist,  // [S, C, 256]
    const float* __restrict__ tmins,  // [S, C]
    const float* __restrict__ tmaxs,  // [S, C]
    float* __restrict__ out,          // [1 + S*C*256]
    float* __restrict__ ws,           // [S*C] per-channel loss partials
    int C, int N)
{
    const int sc = blockIdx.x;
    const int s = sc / C;
    const int c = sc - s * C;
    const float* __restrict__ xc = x + (size_t)c * N;
    const unsigned* __restrict__ wb = bits + (size_t)s * (N >> 5);
    const int tid  = threadIdx.x;
    const int lane = tid & 63;
    const int wid  = tid >> 6;

    __shared__ unsigned int cnt[NB + 1];
    __shared__ float        fsum[NB + 1];
    __shared__ float cdfA[NBINS], cdfB[NBINS];
    __shared__ float Sarr[NBINS];
    __shared__ int   Karr[NBINS];
    __shared__ float wredA[NWAVE], wredB[NWAVE], wredC[NWAVE];
    __shared__ unsigned int scA[BLK], scB[BLK];
    __shared__ float ssA[BLK], ssB[BLK];
    __shared__ float stats[3];   // lo, hi, sumsq

    const int stride = BLK * 32;
    const int Nmain  = (N / stride) * stride;

    // ---------- Phase A: min / max / sum of squares (8x float4 ILP) ----------
    float vmin = 3.4e38f, vmax = -3.4e38f, ssq = 0.f;
    for (int i = tid * 32; i + 31 < Nmain; i += stride) {
        const unsigned w = wb[i >> 5];          // one word == this thread's 32 elems
        float4 a[8];
        #pragma unroll
        for (int q = 0; q < 8; ++q)
            a[q] = *reinterpret_cast<const float4*>(xc + i + q * 4);
        #pragma unroll
        for (int q = 0; q < 8; ++q) {
            const float e[4] = { a[q].x, a[q].y, a[q].z, a[q].w };
            #pragma unroll
            for (int j = 0; j < 4; ++j) {
                const float v = ((w >> (q * 4 + j)) & 1u) ? e[j] : 0.0f;
                vmin = fminf(vmin, v);
                vmax = fmaxf(vmax, v);
                ssq += v * v;
            }
        }
    }
    for (int i = Nmain + tid * 4; i < N; i += BLK * 4) {   // tail (N%128==0 typical)
        const unsigned w = wb[i >> 5] >> (i & 31);
        const float4 xv = *reinterpret_cast<const float4*>(xc + i);
        const float e[4] = { xv.x, xv.y, xv.z, xv.w };
        #pragma unroll
        for (int j = 0; j < 4; ++j) {
            const float v = ((w >> j) & 1u) ? e[j] : 0.0f;
            vmin = fminf(vmin, v); vmax = fmaxf(vmax, v); ssq += v * v;
        }
    }
    #pragma unroll
    for (int off = 32; off > 0; off >>= 1) {
        vmin = fminf(vmin, __shfl_xor(vmin, off));
        vmax = fmaxf(vmax, __shfl_xor(vmax, off));
        ssq += __shfl_xor(ssq, off);
    }
    if (lane == 0) { wredA[wid] = vmin; wredB[wid] = vmax; wredC[wid] = ssq; }
    __syncthreads();
    if (tid == 0) {
        float mn = wredA[0], mx = wredB[0], sq = wredC[0];
        for (int k = 1; k < NWAVE; ++k) {
            mn = fminf(mn, wredA[k]); mx = fmaxf(mx, wredB[k]); sq += wredC[k];
        }
        stats[0] = mn; stats[1] = mx; stats[2] = sq;
    }

    // init LDS for phase B
    for (int i = tid; i < NB + 1; i += BLK) { cnt[i] = 0u; fsum[i] = 0.f; }
    __syncthreads();

    const float lo  = stats[0];
    const float hi  = stats[1];
    const float rng = fmaxf(hi - lo, 1e-12f);
    const float sch  = 255.0f / rng;           // reference hist scale
    const float sc16 = 4080.0f / rng;          // fine grid = 16x the rounded hist grid
    const int ib0 = min(NBINS - 1, max(0, (int)floorf((0.0f - lo) * sch + 0.5f)));
    const int b0  = min(NB - 1,    max(0, (int)floorf((0.0f - lo) * sc16 + 8.0f)));

    // ---------- Phase B: fine buckets (hist derived later) ----------
    unsigned zloc = 0u;
    for (int i = tid * 32; i + 31 < Nmain; i += stride) {
        const unsigned w = wb[i >> 5];
        float4 a[8];
        #pragma unroll
        for (int q = 0; q < 8; ++q)
            a[q] = *reinterpret_cast<const float4*>(xc + i + q * 4);
        #pragma unroll
        for (int q = 0; q < 8; ++q) {
            const float e[4] = { a[q].x, a[q].y, a[q].z, a[q].w };
            #pragma unroll
            for (int j = 0; j < 4; ++j) {
                const float v = ((w >> (q * 4 + j)) & 1u) ? e[j] : 0.0f;
                if (v == 0.0f) {
                    ++zloc;
                } else {
                    const int jb = min(NB - 1, max(0, (int)floorf((v - lo) * sc16 + 8.0f)));
                    atomicAdd(&cnt[jb], 1u);
                    atomicAdd(&fsum[jb], v);
                }
            }
        }
    }
    for (int i = Nmain + tid * 4; i < N; i += BLK * 4) {
        const unsigned w = wb[i >> 5] >> (i & 31);
        const float4 xv = *reinterpret_cast<const float4*>(xc + i);
        const float e[4] = { xv.x, xv.y, xv.z, xv.w };
        #pragma unroll
        for (int j = 0; j < 4; ++j) {
            const float v = ((w >> j) & 1u) ? e[j] : 0.0f;
            if (v == 0.0f) ++zloc;
            else {
                const int jb = min(NB - 1, max(0, (int)floorf((v - lo) * sc16 + 8.0f)));
                atomicAdd(&cnt[jb], 1u);
                atomicAdd(&fsum[jb], v);
            }
        }
    }
    // zero-spike count: wave reduce then 16-way
    #pragma unroll
    for (int off = 32; off > 0; off >>= 1) zloc += __shfl_xor(zloc, off);
    __syncthreads();                       // phase-B atomics done; wred reuse safe
    if (lane == 0) wredA[wid] = (float)zloc;
    __syncthreads();
    unsigned n0 = 0u;
    { float t = 0.f; for (int k = 0; k < NWAVE; ++k) t += wredA[k]; n0 = (unsigned)t; }

    // ---------- target CDF (256 bins) ----------
    float th = 0.f;
    if (tid < NBINS) th = thist[(size_t)sc * NBINS + tid];
    {   // sum over 256 values: wave reduce (only waves 0-3 hold data)
        float t = th;
        #pragma unroll
        for (int off = 32; off > 0; off >>= 1) t += __shfl_xor(t, off);
        if (lane == 0) wredB[wid] = t;
    }
    __syncthreads();
    float tsum = 0.f;
    for (int k = 0; k < 4; ++k) tsum += wredB[k];
    {
        float* srcp = cdfA; float* dstp = cdfB;
        if (tid < NBINS) srcp[tid] = th * ((float)N / fmaxf(tsum, 1e-12f));
        __syncthreads();
        for (int off = 1; off < NBINS; off <<= 1) {   // Hillis-Steele inclusive scan
            if (tid < NBINS) {
                float v = srcp[tid];
                if (tid >= off) v += srcp[tid - off];
                dstp[tid] = v;
            }
            __syncthreads();
            float* tp = srcp; srcp = dstp; dstp = tp;
        }
        if (tid < NBINS) {
            // K_b = #{r in [0,N): r + 0.5 <= cdf[b]}
            const float cdfv = srcp[tid];
            int K = (int)floorf(cdfv - 0.5f) + 1;
            K = min(N, max(0, K));
            if (tid == NBINS - 1) K = N;   // bin 255 runs to N (clip of searchsorted)
            Karr[tid] = K;
        }
    }
    __syncthreads();

    // ---------- Phase C: exclusive prefix over buckets (in place) ----------
    const int base = tid * CHUNK;
    unsigned cacc = 0u; float sacc = 0.f;
    #pragma unroll
    for (int i = 0; i < CHUNK; ++i) {
        const unsigned cc = cnt[base + i];
        const float    sv = fsum[base + i];
        cnt[base + i] = cacc; fsum[base + i] = sacc;
        cacc += cc; sacc += sv;
    }
    scA[tid] = cacc; ssA[tid] = sacc;
    __syncthreads();
    {
        unsigned* cs = scA; unsigned* cd = scB;
        float* fs = ssA; float* fd = ssB;
        for (int off = 1; off < BLK; off <<= 1) {
            unsigned cv = cs[tid]; float fv = fs[tid];
            if (tid >= off) { cv += cs[tid - off]; fv += fs[tid - off]; }
            cd[tid] = cv; fd[tid] = fv;
            __syncthreads();
            unsigned* t1 = cs; cs = cd; cd = t1;
            float*    t2 = fs; fs = fd; fd = t2;
        }
        const unsigned cofs = cs[tid] - cacc;   // exclusive offset for this chunk
        const float    sofs = fs[tid] - sacc;
        for (int i = 0; i < CHUNK; ++i) { cnt[base + i] += cofs; fsum[base + i] += sofs; }
        if (tid == BLK - 1) { cnt[NB] = cs[tid]; fsum[NB] = fs[tid]; }  // sentinels
    }
    __syncthreads();

    // ---------- hist output derived from bucket prefix (16 buckets per bin) ----------
    if (tid < NBINS) {
        unsigned h = cnt[16 * tid + 16] - cnt[16 * tid];
        if (tid == ib0) h += n0;
        out[1 + (size_t)sc * NBINS + tid] = (float)h;
    }

    // ---------- S(K) lookups: sum of k smallest values ----------
    if (tid < NBINS) {
        const unsigned Z0 = cnt[b0];     // nonzeros strictly below zero's bucket
        const float   SZ0 = fsum[b0];
        const unsigned uk = (unsigned)Karr[tid];
        float Sv;
        if (uk <= Z0) {
            int jlo = 0, jhi = b0;
            while (jlo < jhi) {
                const int mid = (jlo + jhi + 1) >> 1;
                if (cnt[mid] <= uk) jlo = mid; else jhi = mid - 1;
            }
            const unsigned d = uk - cnt[jlo];
            Sv = fsum[jlo];
            if (d) Sv += (float)d * (fsum[jlo + 1] - fsum[jlo]) / (float)(cnt[jlo + 1] - cnt[jlo]);
        } else if (uk <= Z0 + n0) {
            Sv = SZ0;                   // zeros contribute 0 to the sum
        } else {
            const unsigned uk2 = uk - n0;
            int jlo = b0, jhi = NB;
            while (jlo < jhi) {
                const int mid = (jlo + jhi + 1) >> 1;
                if (cnt[mid] <= uk2) jlo = mid; else jhi = mid - 1;
            }
            const unsigned d = uk2 - cnt[jlo];
            Sv = fsum[jlo];
            if (d) Sv += (float)d * (fsum[jlo + 1] - fsum[jlo]) / (float)(cnt[jlo + 1] - cnt[jlo]);
        }
        if (tid == NBINS - 1) Sv = fsum[NB];   // S(N) = total sum (zeros add 0)
        Sarr[tid] = Sv;
    }
    __syncthreads();

    // ---------- loss terms ----------
    float term = 0.f;
    if (tid < NBINS) {
        const float tmn = tmins[sc];
        const float tmx = tmaxs[sc];
        const float Tb = ((float)tid / 255.0f) * (tmx - tmn) + tmn;
        const float Sb = Sarr[tid];
        const float Sp = (tid == 0) ? 0.f : Sarr[tid - 1];
        const int   Kb = Karr[tid];
        const int   Kp = (tid == 0) ? 0 : Karr[tid - 1];
        term = -2.0f * Tb * (Sb - Sp) + Tb * Tb * (float)(Kb - Kp);
    }
    #pragma unroll
    for (int off = 32; off > 0; off >>= 1) term += __shfl_xor(term, off);
    __syncthreads();
    if (lane == 0) wredC[wid] = term;
    __syncthreads();
    if (tid == 0) {
        float t = 0.f;
        for (int k = 0; k < 4; ++k) t += wredC[k];
        ws[sc] = (stats[2] + t) / ((float)C * (float)N);
    }
}

__global__ void reduce_loss_kernel(const float* __restrict__ ws,
                                   float* __restrict__ out, int n)
{
    __shared__ float sh[256];
    const int tid = threadIdx.x;
    float v = 0.f;
    for (int i = tid; i < n; i += 256) v += ws[i];
    sh[tid] = v;
    __syncthreads();
    for (int st = 128; st > 0; st >>= 1) {
        if (tid < st) sh[tid] += sh[tid + st];
        __syncthreads();
    }
    if (tid == 0) out[0] = sh[0];
}

extern "C" void kernel_launch(void* const* d_in, const int* in_sizes, int n_in,
                              void* d_out, int out_size, void* d_ws, size_t ws_size,
                              hipStream_t stream)
{
    const float* x     = (const float*)d_in[0];   // [1,C,H,W]
    const float* masks = (const float*)d_in[1];   // [S,H,W]
    const float* thist = (const float*)d_in[2];   // [S,C,256]
    const float* tmins = (const float*)d_in[3];   // [S,C]
    const float* tmaxs = (const float*)d_in[4];   // [S,C]
    float* out = (float*)d_out;
    float* ws  = (float*)d_ws;

    // derive shapes: SC = S*C, C/S = in_sizes[0]/in_sizes[1]
    const int SC = in_sizes[3];
    const long long ratio = (long long)in_sizes[0] / (long long)in_sizes[1];
    const long long csq   = (long long)SC * ratio;
    const int C = (int)(sqrt((double)csq) + 0.5);
    const int S = SC / C;
    const int N = in_sizes[1] / S;
    const int total = in_sizes[1];                 // S*N

    unsigned* bits = (unsigned*)((char*)d_ws + (((size_t)SC * 4 + 255) & ~(size_t)255));

    mask_bits_kernel<<<(total + 1023) / 1024, 1024, 0, stream>>>(masks, bits, total);
    hist_match_kernel<<<SC, BLK, 0, stream>>>(x, bits, thist, tmins, tmaxs, out, ws, C, N);
    reduce_loss_kernel<<<1, 256, 0, stream>>>(ws, out, SC);
}